// Round 1
// baseline (256.809 us; speedup 1.0000x reference)
//
#include <hip/hip_runtime.h>
#include <math.h>

#define BB 32
#define MM 10
#define NNODES 1010
#define DD 128
#define RPB 16   // node rows per block in k_main
#define NG ((NNODES + RPB - 1) / RPB)   // 64

// ---------------------------------------------------------------------------
// Kernel 1: per-(b,m) agent-side small embeddings.
//   - depot_embedding = locs@W_depot.T + alpha * (pe @ W_posproj.T)
//   - agents_embedding = feats @ W_agents.T   -> nodes_embedding rows [0,10)
//   - depot_agents_embedding = concat @ W_depot_agents.T
//   - daWd = depot_agents_embedding @ Wd.T    -> ws
//   - v_pref = Wp @ W_pref[:,0]               -> ws (block 0 only)
// ---------------------------------------------------------------------------
__global__ __launch_bounds__(DD) void k_agents(
    const float* __restrict__ locs,      // (B, 1010, 2)
    const float* __restrict__ capacity,  // (B, 10)
    const float* __restrict__ speed,     // (B, 10)
    const float* __restrict__ W_depot,   // (128, 2)
    const float* __restrict__ W_posproj, // (128, 128)
    const float* __restrict__ alpha,     // (1,)
    const float* __restrict__ W_agents,  // (128, 4)
    const float* __restrict__ W_da,      // (128, 256)
    const float* __restrict__ W_pref,    // (128, 1)
    const float* __restrict__ W_final,   // (128, 384)
    float* __restrict__ out_nodes,       // (B, 1010, 128)
    float* __restrict__ ws_daWd,         // (B, 10, 128)
    float* __restrict__ ws_vpref)        // (128,)
{
    const int b = blockIdx.x / MM;
    const int m = blockIdx.x % MM;
    const int d = threadIdx.x;

    __shared__ float pe_s[DD];
    __shared__ float dep_s[DD];
    __shared__ float ag_s[DD];
    __shared__ float da_s[DD];

    // positional encoding element pe[m][d]
    {
        const int i = d >> 1;
        const float div = expf((float)(2 * i) * (-logf(10000.0f) / (float)DD));
        const float ang = (float)m * div;
        pe_s[d] = (d & 1) ? cosf(ang) : sinf(ang);
    }
    __syncthreads();

    // peproj[d] = dot(pe[m,:], W_posproj[d,:])
    float pp = 0.0f;
    {
        const float4* wp = (const float4*)(W_posproj + (size_t)d * DD);
        #pragma unroll 4
        for (int k4 = 0; k4 < DD / 4; ++k4) {
            float4 w = wp[k4];
            const float* p = &pe_s[k4 * 4];
            pp = fmaf(w.x, p[0], pp);
            pp = fmaf(w.y, p[1], pp);
            pp = fmaf(w.z, p[2], pp);
            pp = fmaf(w.w, p[3], pp);
        }
    }

    const float lx = locs[((size_t)b * NNODES + m) * 2 + 0];
    const float ly = locs[((size_t)b * NNODES + m) * 2 + 1];
    const float dep = fmaf(lx, W_depot[d * 2 + 0],
                      fmaf(ly, W_depot[d * 2 + 1], alpha[0] * pp));

    const float cap = capacity[b * MM + m] * (1.0f / 40.0f);
    const float spd = speed[b * MM + m];  // SPEED_SCALER = 1
    const float ag = fmaf(lx, W_agents[d * 4 + 0],
                     fmaf(ly, W_agents[d * 4 + 1],
                     fmaf(cap, W_agents[d * 4 + 2],
                          spd * W_agents[d * 4 + 3])));

    out_nodes[((size_t)b * NNODES + m) * DD + d] = ag;

    dep_s[d] = dep;
    ag_s[d] = ag;
    __syncthreads();

    // depot_agents_embedding[d] = dot(concat(dep, ag), W_da[d,:256])
    float da = 0.0f;
    {
        const float4* wda = (const float4*)(W_da + (size_t)d * 2 * DD);
        #pragma unroll 4
        for (int k4 = 0; k4 < DD / 4; ++k4) {
            float4 w = wda[k4];
            const float* p = &dep_s[k4 * 4];
            da = fmaf(w.x, p[0], da);
            da = fmaf(w.y, p[1], da);
            da = fmaf(w.z, p[2], da);
            da = fmaf(w.w, p[3], da);
        }
        #pragma unroll 4
        for (int k4 = 0; k4 < DD / 4; ++k4) {
            float4 w = wda[DD / 4 + k4];
            const float* p = &ag_s[k4 * 4];
            da = fmaf(w.x, p[0], da);
            da = fmaf(w.y, p[1], da);
            da = fmaf(w.z, p[2], da);
            da = fmaf(w.w, p[3], da);
        }
    }
    da_s[d] = da;
    __syncthreads();

    // daWd[d] = dot(da, W_final[d, 256:384])
    float dw = 0.0f;
    {
        const float4* wfd = (const float4*)(W_final + (size_t)d * 3 * DD + 2 * DD);
        #pragma unroll 4
        for (int k4 = 0; k4 < DD / 4; ++k4) {
            float4 w = wfd[k4];
            const float* p = &da_s[k4 * 4];
            dw = fmaf(w.x, p[0], dw);
            dw = fmaf(w.y, p[1], dw);
            dw = fmaf(w.z, p[2], dw);
            dw = fmaf(w.w, p[3], dw);
        }
    }
    ws_daWd[(b * MM + m) * DD + d] = dw;

    if (blockIdx.x == 0) {
        // v_pref[d] = dot(W_final[d, 128:256], W_pref[:,0])
        float vp = 0.0f;
        const float4* wfp = (const float4*)(W_final + (size_t)d * 3 * DD + DD);
        const float4* prf = (const float4*)W_pref;
        #pragma unroll 4
        for (int k4 = 0; k4 < DD / 4; ++k4) {
            float4 w = wfp[k4];
            float4 p = prf[k4];
            vp = fmaf(w.x, p.x, vp);
            vp = fmaf(w.y, p.y, vp);
            vp = fmaf(w.z, p.z, vp);
            vp = fmaf(w.w, p.w, vp);
        }
        ws_vpref[d] = vp;
    }
}

// ---------------------------------------------------------------------------
// Kernel 2: per 16-node-row group of one batch.
//   phase A: client embeddings -> nodes_embedding + LDS rows
//   phase B: nwn[d] = dot(row, Wn[d,:]) with Wn chunks in registers
//   phase C: combined = nwn + pref * v_pref + daWd  (fused expansion)
// ---------------------------------------------------------------------------
__global__ __launch_bounds__(DD) void k_main(
    const float* __restrict__ locs,      // (B, 1010, 2)
    const float* __restrict__ demand,    // (B, 1, 1010)
    const float* __restrict__ pref,      // (B, 10, 1010)
    const float* __restrict__ W_clients, // (128, 5)
    const float* __restrict__ W_final,   // (128, 384)
    const float* __restrict__ ws_daWd,   // (B, 10, 128)
    const float* __restrict__ ws_vpref,  // (128,)
    float* __restrict__ out_nodes,       // (B, 1010, 128)
    float* __restrict__ out_comb)        // (B, 10, 1010, 128)
{
    const int g = blockIdx.x;
    const int b = blockIdx.y;
    const int tid = threadIdx.x;
    const int n0 = g * RPB;

    __shared__ float rows[RPB][DD];   // 8 KB
    __shared__ float feat[RPB][5];

    // per-row client scalar features (threads 0..15)
    if (tid < RPB) {
        const int node = n0 + tid;
        if (node < NNODES && node >= MM) {
            const float cx = locs[((size_t)b * NNODES + node) * 2 + 0];
            const float cy = locs[((size_t)b * NNODES + node) * 2 + 1];
            const float d0x = locs[((size_t)b * NNODES + 0) * 2 + 0];
            const float d0y = locs[((size_t)b * NNODES + 0) * 2 + 1];
            const float dx = cx - d0x;
            const float dy = cy - d0y;
            feat[tid][0] = cx;
            feat[tid][1] = cy;
            feat[tid][2] = demand[(size_t)b * NNODES + node] * (1.0f / 40.0f);
            feat[tid][3] = sqrtf(fmaf(dx, dx, dy * dy));
            feat[tid][4] = atan2f(dy, dx);
        }
    }
    __syncthreads();

    // phase A: fill rows[r][tid] with nodes_embedding value
    {
        const float wc0 = W_clients[tid * 5 + 0];
        const float wc1 = W_clients[tid * 5 + 1];
        const float wc2 = W_clients[tid * 5 + 2];
        const float wc3 = W_clients[tid * 5 + 3];
        const float wc4 = W_clients[tid * 5 + 4];
        #pragma unroll
        for (int r = 0; r < RPB; ++r) {
            const int node = n0 + r;
            float val = 0.0f;
            if (node < NNODES) {
                if (node < MM) {
                    val = out_nodes[((size_t)b * NNODES + node) * DD + tid];
                } else {
                    val = fmaf(feat[r][0], wc0,
                          fmaf(feat[r][1], wc1,
                          fmaf(feat[r][2], wc2,
                          fmaf(feat[r][3], wc3,
                               feat[r][4] * wc4))));
                    out_nodes[((size_t)b * NNODES + node) * DD + tid] = val;
                }
            }
            rows[r][tid] = val;
        }
    }
    __syncthreads();

    // phase B: acc[r] = dot(rows[r][:], W_final[d, 0:128])
    const int d = tid;
    float acc[RPB];
    #pragma unroll
    for (int r = 0; r < RPB; ++r) acc[r] = 0.0f;

    {
        const float4* wn = (const float4*)(W_final + (size_t)d * 3 * DD);
        #pragma unroll 4
        for (int k4 = 0; k4 < DD / 4; ++k4) {
            const float4 w = wn[k4];
            #pragma unroll
            for (int r = 0; r < RPB; ++r) {
                const float4 p = *(const float4*)&rows[r][k4 * 4];
                acc[r] = fmaf(w.x, p.x,
                         fmaf(w.y, p.y,
                         fmaf(w.z, p.z,
                         fmaf(w.w, p.w, acc[r]))));
            }
        }
    }

    // phase C: fused broadcast expansion
    const float vp = ws_vpref[d];
    float dawd[MM];
    #pragma unroll
    for (int mm = 0; mm < MM; ++mm)
        dawd[mm] = ws_daWd[(b * MM + mm) * DD + d];

    for (int r = 0; r < RPB; ++r) {
        const int node = n0 + r;
        if (node >= NNODES) break;
        #pragma unroll
        for (int mm = 0; mm < MM; ++mm) {
            const float pr = pref[(size_t)(b * MM + mm) * NNODES + node];
            out_comb[((size_t)(b * MM + mm) * NNODES + node) * DD + d] =
                fmaf(pr, vp, acc[r] + dawd[mm]);
        }
    }
}

extern "C" void kernel_launch(void* const* d_in, const int* in_sizes, int n_in,
                              void* d_out, int out_size, void* d_ws, size_t ws_size,
                              hipStream_t stream) {
    const float* locs       = (const float*)d_in[0];
    const float* capacity   = (const float*)d_in[1];
    const float* speed      = (const float*)d_in[2];
    const float* demand     = (const float*)d_in[3];
    const float* agents_pref= (const float*)d_in[4];
    // d_in[5] action_mask: only its shape is used by the reference
    const float* W_depot    = (const float*)d_in[6];
    const float* W_posproj  = (const float*)d_in[7];
    const float* alpha      = (const float*)d_in[8];
    const float* W_agents   = (const float*)d_in[9];
    const float* W_da       = (const float*)d_in[10];
    const float* W_clients  = (const float*)d_in[11];
    const float* W_pref     = (const float*)d_in[12];
    const float* W_final    = (const float*)d_in[13];

    float* out_nodes = (float*)d_out;                         // 32*1010*128
    float* out_comb  = out_nodes + (size_t)BB * NNODES * DD;  // 32*10*1010*128

    float* ws_daWd  = (float*)d_ws;                 // 32*10*128 floats
    float* ws_vpref = ws_daWd + BB * MM * DD;       // 128 floats

    k_agents<<<dim3(BB * MM), DD, 0, stream>>>(
        locs, capacity, speed, W_depot, W_posproj, alpha, W_agents,
        W_da, W_pref, W_final, out_nodes, ws_daWd, ws_vpref);

    k_main<<<dim3(NG, BB), DD, 0, stream>>>(
        locs, demand, agents_pref, W_clients, W_final,
        ws_daWd, ws_vpref, out_nodes, out_comb);
}